// Round 9
// baseline (193.192 us; speedup 1.0000x reference)
//
#include <hip/hip_runtime.h>
#include <hip/hip_bf16.h>
#include <math.h>

#define BB 16
#define IC 64
#define CH 128
#define LL 16384
#define KS 5
#define CAK 5
#define KCR 76
#define EPSV 1e-5f
#define NLT2 256          // psum/pmax partials per (b,c): 128 l-tiles x 2 half-waves
#define EPSR 8e-3f        // F_max candidate-slot window (>> 6 sigma of f16-conv error)

typedef _Float16 f16x8 __attribute__((ext_vector_type(8)));
typedef float f32x16 __attribute__((ext_vector_type(16)));

// ---- workspace layout (in floats) ----
#define OFF_WPACK 0                          // 40960 ushort = 20480 floats (f16 A-frags)
#define OFF_W2F   20480                      // 40960 fp32 folded weights [c][k][i]
#define OFF_BIAS2 (OFF_W2F + 40960)          // 128
#define OFF_PSUM  (OFF_BIAS2 + CH)           // 16*128*256
#define OFF_PMAX  (OFF_PSUM + BB*CH*NLT2)
#define OFF_FADD  (OFF_PMAX + BB*CH*NLT2)    // 2048
#define OFF_CM    (OFF_FADD + BB*CH)
#define OFF_MASK  (OFF_CM + BB*CH)
#define OFF_F16   (OFF_MASK + BB*CH)         // fp16 f: BB*CH*LL ushorts

__device__ __forceinline__ unsigned short f2h(float f) {
    _Float16 h = (_Float16)f;
    return __builtin_bit_cast(unsigned short, h);
}
__device__ __forceinline__ float h2f(unsigned short u) {
    _Float16 h = __builtin_bit_cast(_Float16, u);
    return (float)h;
}

// DPP lane-shift (VALU pipe, no LDS). bound_ctrl=true: invalid lanes -> 0.
template<int CTRL>
__device__ __forceinline__ float dppf(float v) {
    return __builtin_bit_cast(float,
        __builtin_amdgcn_update_dpp(0, __builtin_bit_cast(int, v), CTRL, 0xF, 0xF, true));
}
__device__ __forceinline__ float dpp_sum32(float s) {
    s += dppf<0x111>(s);
    s += dppf<0x112>(s);
    s += dppf<0x114>(s);
    s += dppf<0x118>(s);
    s += dppf<0x142>(s);   // row_bcast:15 -> totals in lanes 31/63
    return s;
}
__device__ __forceinline__ float dpp_max32(float m) {
    m = fmaxf(m, dppf<0x111>(m));
    m = fmaxf(m, dppf<0x112>(m));
    m = fmaxf(m, dppf<0x114>(m));
    m = fmaxf(m, dppf<0x118>(m));
    m = fmaxf(m, dppf<0x142>(m));
    return m;
}

// ---------------------------------------------------------------------------
// Prep: fold BN scale into conv weights. Outputs:
//  - wpack (f16) in per-lane MFMA A-fragment order:
//      wpack[(((ch2*2+mt)*20+s)*64+ln)*8+j]
//      c = ch2*64 + mt*32 + (ln&31); kk = s>>2; i = (s&3)*16 + (ln>>5)*8 + j
//  - w2f (fp32) [c][kk][i] for the exact F_max refinement
//  - bias2
// ---------------------------------------------------------------------------
__global__ void prep_kernel(const float* __restrict__ conv_w, const float* __restrict__ conv_b,
                            const float* __restrict__ bn_g, const float* __restrict__ bn_b,
                            const float* __restrict__ bn_m, const float* __restrict__ bn_v,
                            unsigned short* __restrict__ wpack, float* __restrict__ w2f,
                            float* __restrict__ bias2)
{
    int e = blockIdx.x * 256 + threadIdx.x;
    if (e < 4 * 20 * 64 * 8) {             // 40960 f16 A-frag entries
        int j    = e & 7;
        int ln   = (e >> 3) & 63;
        int rest = e >> 9;                 // 0..79
        int s    = rest % 20;
        int mt   = (rest / 20) & 1;
        int ch2  = rest / 40;
        int c  = ch2 * 64 + mt * 32 + (ln & 31);
        int kk = s >> 2;
        int i  = (s & 3) * 16 + (ln >> 5) * 8 + j;
        float inv = bn_g[c] * rsqrtf(bn_v[c] + EPSV);
        wpack[e] = f2h(conv_w[(c * IC + i) * KS + kk] * inv);
    }
    if (e < CH * KS * IC) {                // 40960 fp32 [c][kk][i]
        int i  = e & 63;
        int kk = (e >> 6) % KS;
        int c  = e / (KS * IC);
        float inv = bn_g[c] * rsqrtf(bn_v[c] + EPSV);
        w2f[e] = conv_w[(c * IC + i) * KS + kk] * inv;
    }
    if (e < CH) {
        float inv = bn_g[e] * rsqrtf(bn_v[e] + EPSV);
        bias2[e] = (conv_b[e] - bn_m[e]) * inv + bn_b[e];
    }
}

// ---------------------------------------------------------------------------
// Single-pass f16 MFMA conv + BN + ReLU -> f (fp16, ws) + per-channel partial
// sum/max (DPP, from fp32 accumulators). Block = 128c x 128l, 4 waves of
// (64c x 64l). LDS xs[136 rows(l)][64 i] f16, 16B chunks XOR-swizzled (row&7).
// ---------------------------------------------------------------------------
__global__ __launch_bounds__(256, 4)
void conv_mfma_kernel(const float* __restrict__ x,
                      const unsigned short* __restrict__ wpack,
                      const float* __restrict__ bias2,
                      unsigned short* __restrict__ f16,
                      float* __restrict__ psum, float* __restrict__ pmax)
{
    __shared__ unsigned short xs[136 * 64];    // 17,408 B
    const int b   = blockIdx.x;
    const int lt  = blockIdx.y;
    const int l0  = lt * 128;
    const int tid = threadIdx.x;
    const int ln  = tid & 63;
    const int wv  = __builtin_amdgcn_readfirstlane(tid >> 6);

    // ---- staging: wave wv owns i in [wv*16, wv*16+16); lane = row (l) ----
    const float* xb = x + (size_t)b * (IC * LL);
    const int ibase = wv * 16;
    #pragma unroll
    for (int g = 0; g < 3; ++g) {
        int row = g * 64 + ln;
        int l   = l0 - 4 + row;
        if (row < 136) {
            bool vl = (l >= 0) && (l < LL);
            float v[16];
            #pragma unroll
            for (int q = 0; q < 16; ++q)
                v[q] = vl ? xb[(size_t)(ibase + q) * LL + l] : 0.0f;
            unsigned short h[16];
            #pragma unroll
            for (int q = 0; q < 16; ++q) h[q] = f2h(v[q]);
            int rs = row & 7;
            #pragma unroll
            for (int q2 = 0; q2 < 2; ++q2) {     // two 8-f16 (16B) chunks
                int i0    = ibase + q2 * 8;
                int chunk = (i0 >> 3) ^ rs;
                uint4 w4;
                w4.x = (unsigned)h[q2*8+0] | ((unsigned)h[q2*8+1] << 16);
                w4.y = (unsigned)h[q2*8+2] | ((unsigned)h[q2*8+3] << 16);
                w4.z = (unsigned)h[q2*8+4] | ((unsigned)h[q2*8+5] << 16);
                w4.w = (unsigned)h[q2*8+6] | ((unsigned)h[q2*8+7] << 16);
                *(uint4*)&xs[row * 64 + chunk * 8] = w4;
            }
        }
    }
    __syncthreads();

    const int ch2  = wv >> 1;   // c-half
    const int lh   = wv & 1;    // l-half
    const int ln31 = ln & 31;
    const int hi   = ln >> 5;
    const int rowbase = lh * 64 + ln31 + 2;

    const unsigned short* wp  = wpack + (size_t)ln * 8;
    const unsigned short* pA0 = wp + (size_t)((ch2 * 2 + 0) * 20) * 512;  // mt0
    const unsigned short* pA1 = wp + (size_t)((ch2 * 2 + 1) * 20) * 512;  // mt1

    f32x16 acc[2][2];
    #pragma unroll
    for (int mt = 0; mt < 2; ++mt)
        #pragma unroll
        for (int nt = 0; nt < 2; ++nt)
            #pragma unroll
            for (int r = 0; r < 16; ++r) acc[mt][nt][r] = 0.0f;

    auto loadA = [&](f16x8* Av, int s) {
        Av[0] = *(const f16x8*)(pA0 + (size_t)s * 512);
        Av[1] = *(const f16x8*)(pA1 + (size_t)s * 512);
    };
    auto loadB = [&](f16x8* Bv, int s) {
        int kk = s >> 2, iq = s & 3;
        int r0 = rowbase + kk;
        int r1 = r0 + 32;
        int c0 = ((iq << 1) + hi) ^ (r0 & 7);
        int c1 = ((iq << 1) + hi) ^ (r1 & 7);
        Bv[0] = *(const f16x8*)&xs[r0 * 64 + c0 * 8];   // nt0
        Bv[1] = *(const f16x8*)&xs[r1 * 64 + c1 * 8];   // nt1
    };
    auto compute = [&](const f16x8* Av, const f16x8* Bv) {
        acc[0][0] = __builtin_amdgcn_mfma_f32_32x32x16_f16(Av[0], Bv[0], acc[0][0], 0, 0, 0);
        acc[1][0] = __builtin_amdgcn_mfma_f32_32x32x16_f16(Av[1], Bv[0], acc[1][0], 0, 0, 0);
        acc[0][1] = __builtin_amdgcn_mfma_f32_32x32x16_f16(Av[0], Bv[1], acc[0][1], 0, 0, 0);
        acc[1][1] = __builtin_amdgcn_mfma_f32_32x32x16_f16(Av[1], Bv[1], acc[1][1], 0, 0, 0);
    };

    // ---- main loop: 2-deep A/B rings over 20 K-slices ----
    f16x8 Ar[2][2], Br[2][2];
    loadA(Ar[0], 0); loadB(Br[0], 0);
    #pragma unroll
    for (int s = 0; s < 20; ++s) {
        if (s + 1 < 20) { loadA(Ar[(s + 1) & 1], s + 1); loadB(Br[(s + 1) & 1], s + 1); }
        compute(Ar[s & 1], Br[s & 1]);
    }

    // ---- epilogue: bias + relu, store f16, per-channel partial sum/max ----
    // D mapping (32x32): col(l)=ln&31, row(c)=(r&3)+8*(r>>2)+4*(ln>>5)
    const int lgbase = l0 + lh * 64 + ln31;
    #pragma unroll
    for (int mt = 0; mt < 2; ++mt) {
        #pragma unroll
        for (int nt = 0; nt < 2; ++nt) {
            #pragma unroll
            for (int r = 0; r < 16; ++r) {
                int c = ch2 * 64 + mt * 32 + (r & 3) + 8 * (r >> 2) + 4 * hi;
                float fv = fmaxf(acc[mt][nt][r] + bias2[c], 0.0f);
                f16[((size_t)(b * CH + c)) * LL + lgbase + nt * 32] = f2h(fv);
                acc[mt][nt][r] = fv;
            }
        }
    }
    #pragma unroll
    for (int mt = 0; mt < 2; ++mt) {
        #pragma unroll
        for (int r = 0; r < 16; ++r) {
            float s = dpp_sum32(acc[mt][0][r] + acc[mt][1][r]);
            float m = dpp_max32(fmaxf(acc[mt][0][r], acc[mt][1][r]));
            if (ln31 == 31) {
                int c   = ch2 * 64 + mt * 32 + (r & 3) + 8 * (r >> 2) + 4 * hi;
                int lt2 = lt * 2 + lh;
                psum[(b * CH + c) * NLT2 + lt2] = s;
                pmax[(b * CH + c) * NLT2 + lt2] = m;
            }
        }
    }
}

// ---------------------------------------------------------------------------
// fixmax: per (b,c) — one 64-lane block. F_avg from psum (error ~5e-6,
// harmless). F_max recomputed EXACTLY: flag pmax slots within EPSR of the
// approx max (per-element f16-conv error << EPSR), recompute those 64-l slots
// in fp32 VALU conv (x is L3-hot), take the exact max. Writes
// fadd = (alpha+0.5)*F_avg + (beta+0.5)*F_max_exact.
// ---------------------------------------------------------------------------
__global__ __launch_bounds__(64)
void fixmax_kernel(const float* __restrict__ x, const float* __restrict__ w2f,
                   const float* __restrict__ bias2,
                   const float* __restrict__ psum, const float* __restrict__ pmax,
                   const float* __restrict__ alpha, const float* __restrict__ beta,
                   float* __restrict__ fadd)
{
    const int c  = blockIdx.x;
    const int b  = blockIdx.y;
    const int ln = threadIdx.x;
    const float* ps = psum + (size_t)(b * CH + c) * NLT2;
    const float* pm = pmax + (size_t)(b * CH + c) * NLT2;

    float pmg[4], s4 = 0.0f, m4 = 0.0f;
    #pragma unroll
    for (int g = 0; g < 4; ++g) {
        pmg[g] = pm[g * 64 + ln];
        s4 += ps[g * 64 + ln];
        m4 = fmaxf(m4, pmg[g]);
    }
    float stot = s4, M = m4;
    #pragma unroll
    for (int off = 1; off <= 32; off <<= 1) {
        stot += __shfl_xor(stot, off, 64);
        M = fmaxf(M, __shfl_xor(M, off, 64));
    }

    // exact recompute of candidate slots
    const float* xb  = x + (size_t)b * (IC * LL);
    const float* w2c = w2f + (size_t)c * (KS * IC);
    const float bsc  = bias2[c];
    float Fmax = 0.0f;
    int cnt = 0;
    #pragma unroll
    for (int g = 0; g < 4 && cnt < 8; ++g) {
        unsigned long long bal = __ballot(pmg[g] >= M - EPSR);
        while (bal && cnt < 8) {
            int sl = __ffsll((long long)bal) - 1;
            bal &= bal - 1;
            ++cnt;
            int slot = g * 64 + sl;
            int l    = (slot >> 1) * 128 + (slot & 1) * 64 + ln;
            float fe = bsc;
            #pragma unroll
            for (int kk = 0; kk < KS; ++kk) {
                int lidx = l + kk - 2;
                bool v = (lidx >= 0) && (lidx < LL);
                const float* xr = xb + lidx;
                const float* wr = w2c + kk * IC;
                for (int i = 0; i < IC; ++i) {
                    float xv = v ? xr[(size_t)i * LL] : 0.0f;
                    fe = fmaf(xv, wr[i], fe);
                }
            }
            fe = fmaxf(fe, 0.0f);
            #pragma unroll
            for (int off = 1; off <= 32; off <<= 1)
                fe = fmaxf(fe, __shfl_xor(fe, off, 64));
            Fmax = fmaxf(Fmax, fe);
        }
    }

    if (ln == 0) {
        float favg = stot * (1.0f / LL);
        fadd[b * CH + c] = (alpha[0] + 0.5f) * favg + (beta[0] + 0.5f) * Fmax;
    }
}

// ---------------------------------------------------------------------------
// chan2: per batch — channel attention (5-tap conv over C + sigmoid) from
// fadd, then top-K mask via rank count (ties by lower index = jax.lax.top_k).
// ---------------------------------------------------------------------------
__global__ void chan2_kernel(const float* __restrict__ fadd,
                             const float* __restrict__ ca_w, const float* __restrict__ ca_b,
                             float* __restrict__ cm, float* __restrict__ maskv)
{
    int b = blockIdx.x;
    int c = threadIdx.x;   // 128
    __shared__ float fa[CH];
    __shared__ float cms[CH];
    fa[c] = fadd[b * CH + c];
    __syncthreads();

    float z = ca_b[0];
    #pragma unroll
    for (int k = 0; k < CAK; ++k) {
        int cc = c + k - 2;
        float v = (cc >= 0 && cc < CH) ? fa[cc] : 0.0f;
        z = fmaf(ca_w[k], v, z);
    }
    float cmv = 1.0f / (1.0f + expf(-z));
    cms[c] = cmv;
    __syncthreads();

    int rank = 0;
    for (int cc = 0; cc < CH; ++cc) {
        float o = cms[cc];
        rank += (o > cmv || (o == cmv && cc < c)) ? 1 : 0;
    }
    cm[b * CH + c] = cmv;
    maskv[b * CH + c] = (rank < KCR) ? 1.0f : 0.0f;
}

// ---------------------------------------------------------------------------
// Fused stats + gate + final, vectorized x2 along l (from round 8).
// ---------------------------------------------------------------------------
__global__ __launch_bounds__(256)
void sgf_kernel(const unsigned short* __restrict__ f16, float* __restrict__ out,
                const float* __restrict__ cm, const float* __restrict__ maskv,
                const float* __restrict__ sa_w,
                const float* __restrict__ sabn_g, const float* __restrict__ sabn_b,
                const float* __restrict__ sabn_m, const float* __restrict__ sabn_v)
{
    __shared__ float cms[CH], mks[CH];
    __shared__ float st[4][520];
    const int g   = blockIdx.x;    // 0..31 (512-l tile)
    const int b   = blockIdx.y;
    const int l0  = g * 512;
    const int tid = threadIdx.x;
    if (tid < CH) { cms[tid] = cm[b * CH + tid]; mks[tid] = maskv[b * CH + tid]; }
    __syncthreads();

    {
        const unsigned short* fb = f16 + (size_t)b * CH * LL + l0 + 2 * tid;
        float cmx0 = 0.f, csm0 = 0.f, smx0 = 0.f, ssm0 = 0.f;
        float cmx1 = 0.f, csm1 = 0.f, smx1 = 0.f, ssm1 = 0.f;
        #pragma unroll 4
        for (int c = 0; c < CH; ++c) {
            unsigned pr = *(const unsigned*)(fb + (size_t)c * LL);
            float cmc = cms[c], mk = mks[c];
            float v0 = h2f((unsigned short)(pr & 0xFFFFu)) * cmc;
            float v1 = h2f((unsigned short)(pr >> 16)) * cmc;
            float vs0 = v0 * mk, vu0 = v0 - vs0;
            float vs1 = v1 * mk, vu1 = v1 - vs1;
            cmx0 = fmaxf(cmx0, vs0); smx0 = fmaxf(smx0, vu0); csm0 += vs0; ssm0 += vu0;
            cmx1 = fmaxf(cmx1, vs1); smx1 = fmaxf(smx1, vu1); csm1 += vs1; ssm1 += vu1;
        }
        int s0 = 3 + 2 * tid;
        st[0][s0] = cmx0;                  st[0][s0 + 1] = cmx1;
        st[1][s0] = csm0 * (1.0f / KCR);   st[1][s0 + 1] = csm1 * (1.0f / KCR);
        st[2][s0] = smx0;                  st[2][s0 + 1] = smx1;
        st[3][s0] = ssm0 * (1.0f / (CH - KCR));
        st[3][s0 + 1] = ssm1 * (1.0f / (CH - KCR));
    }
    if (tid < 6) {
        int slot = (tid < 3) ? tid : 515 + (tid - 3);
        int l = l0 - 3 + slot;
        float cmx = 0.f, csm = 0.f, smx = 0.f, ssm = 0.f;
        if (l >= 0 && l < LL) {
            const unsigned short* fb = f16 + (size_t)b * CH * LL + l;
            for (int c = 0; c < CH; ++c) {
                float v  = h2f(fb[(size_t)c * LL]) * cms[c];
                float mk = mks[c];
                float vs = v * mk, vu = v - vs;
                cmx = fmaxf(cmx, vs); smx = fmaxf(smx, vu);
                csm += vs; ssm += vu;
            }
        }
        st[0][slot] = cmx;
        st[1][slot] = csm * (1.0f / KCR);
        st[2][slot] = smx;
        st[3][slot] = ssm * (1.0f / (CH - KCR));
    }
    __syncthreads();

    float inv = sabn_g[0] * rsqrtf(sabn_v[0] + EPSV);
    float bb2 = sabn_b[0] - sabn_m[0] * inv;
    float y1a = 0.f, y2a = 0.f, y1b = 0.f, y2b = 0.f;
    #pragma unroll
    for (int k = 0; k < 7; ++k) {
        float wm = sa_w[k], wa = sa_w[7 + k];
        int s0 = 2 * tid + k;
        y1a = fmaf(wm, st[0][s0],     fmaf(wa, st[1][s0],     y1a));
        y2a = fmaf(wm, st[2][s0],     fmaf(wa, st[3][s0],     y2a));
        y1b = fmaf(wm, st[0][s0 + 1], fmaf(wa, st[1][s0 + 1], y1b));
        y2b = fmaf(wm, st[2][s0 + 1], fmaf(wa, st[3][s0 + 1], y2b));
    }
    float A1a = 1.0f / (1.0f + expf(-fmaxf(y1a * inv + bb2, 0.f)));
    float A2a = 1.0f / (1.0f + expf(-fmaxf(y2a * inv + bb2, 0.f)));
    float A1b = 1.0f / (1.0f + expf(-fmaxf(y1b * inv + bb2, 0.f)));
    float A2b = 1.0f / (1.0f + expf(-fmaxf(y2b * inv + bb2, 0.f)));

    const unsigned short* fb = f16 + (size_t)b * CH * LL + l0 + 2 * tid;
    float* ob = out + (size_t)b * CH * LL + l0 + 2 * tid;
    #pragma unroll 4
    for (int c = 0; c < CH; ++c) {
        unsigned pr = *(const unsigned*)(fb + (size_t)c * LL);
        float cmc = cms[c];
        float v0 = h2f((unsigned short)(pr & 0xFFFFu)) * cmc;
        float v1 = h2f((unsigned short)(pr >> 16)) * cmc;
        bool sel = (mks[c] > 0.5f);
        float2 w;
        w.x = v0 * (sel ? A1a : A2a);
        w.y = v1 * (sel ? A1b : A2b);
        *(float2*)(ob + (size_t)c * LL) = w;
    }
}

extern "C" void kernel_launch(void* const* d_in, const int* in_sizes, int n_in,
                              void* d_out, int out_size, void* d_ws, size_t ws_size,
                              hipStream_t stream)
{
    const float* x      = (const float*)d_in[0];
    const float* conv_w = (const float*)d_in[1];
    const float* conv_b = (const float*)d_in[2];
    const float* bn_g   = (const float*)d_in[3];
    const float* bn_b   = (const float*)d_in[4];
    const float* bn_m   = (const float*)d_in[5];
    const float* bn_v   = (const float*)d_in[6];
    const float* alpha  = (const float*)d_in[7];
    const float* beta   = (const float*)d_in[8];
    const float* ca_w   = (const float*)d_in[9];
    const float* ca_b   = (const float*)d_in[10];
    const float* sa_w   = (const float*)d_in[11];
    const float* sabn_g = (const float*)d_in[12];
    const float* sabn_b = (const float*)d_in[13];
    const float* sabn_m = (const float*)d_in[14];
    const float* sabn_v = (const float*)d_in[15];

    float* out = (float*)d_out;
    float* ws  = (float*)d_ws;

    unsigned short* wpack = (unsigned short*)(ws + OFF_WPACK);
    float* w2f   = ws + OFF_W2F;
    float* bias2 = ws + OFF_BIAS2;
    float* psum  = ws + OFF_PSUM;
    float* pmax  = ws + OFF_PMAX;
    float* faddp = ws + OFF_FADD;
    float* cmv_  = ws + OFF_CM;
    float* mskv  = ws + OFF_MASK;
    unsigned short* f16p = (unsigned short*)(ws + OFF_F16);

    prep_kernel<<<160, 256, 0, stream>>>(conv_w, conv_b, bn_g, bn_b, bn_m, bn_v,
                                         wpack, w2f, bias2);

    conv_mfma_kernel<<<dim3(BB, 128), 256, 0, stream>>>(x, wpack, bias2, f16p, psum, pmax);

    fixmax_kernel<<<dim3(CH, BB), 64, 0, stream>>>(x, w2f, bias2, psum, pmax,
                                                   alpha, beta, faddp);

    chan2_kernel<<<BB, CH, 0, stream>>>(faddp, ca_w, ca_b, cmv_, mskv);

    sgf_kernel<<<dim3(32, BB), 256, 0, stream>>>(f16p, out, cmv_, mskv, sa_w,
                                                 sabn_g, sabn_b, sabn_m, sabn_v);
}

// Round 10
// 180.563 us; speedup vs baseline: 1.0699x; 1.0699x over previous
//
#include <hip/hip_runtime.h>
#include <hip/hip_bf16.h>
#include <math.h>

#define BB 16
#define IC 64
#define CH 128
#define LL 16384
#define KS 5
#define CAK 5
#define KCR 76
#define EPSV 1e-5f
#define NLT2 256          // psum/pmax partials per (b,c): 128 l-tiles x 2 half-waves
#define EPSR 5e-3f        // F_max candidate window (>8 sigma of f16-conv error model)

typedef _Float16 f16x8 __attribute__((ext_vector_type(8)));
typedef float f32x16 __attribute__((ext_vector_type(16)));

// ---- workspace layout (in floats) ----
#define OFF_WPACK 0                          // 40960 ushort = 20480 floats (f16 A-frags)
#define OFF_W2F   20480                      // 40960 fp32 folded weights [c][k][i]
#define OFF_BIAS2 (OFF_W2F + 40960)          // 128
#define OFF_PSUM  (OFF_BIAS2 + CH)           // 16*128*256
#define OFF_PMAX  (OFF_PSUM + BB*CH*NLT2)
#define OFF_FADD  (OFF_PMAX + BB*CH*NLT2)    // 2048
#define OFF_CM    (OFF_FADD + BB*CH)
#define OFF_MASK  (OFF_CM + BB*CH)
#define OFF_F16   (OFF_MASK + BB*CH)         // fp16 f: BB*CH*LL ushorts

__device__ __forceinline__ unsigned short f2h(float f) {
    _Float16 h = (_Float16)f;
    return __builtin_bit_cast(unsigned short, h);
}
__device__ __forceinline__ float h2f(unsigned short u) {
    _Float16 h = __builtin_bit_cast(_Float16, u);
    return (float)h;
}

// DPP lane-shift (VALU pipe, no LDS). bound_ctrl=true: invalid lanes -> 0.
template<int CTRL>
__device__ __forceinline__ float dppf(float v) {
    return __builtin_bit_cast(float,
        __builtin_amdgcn_update_dpp(0, __builtin_bit_cast(int, v), CTRL, 0xF, 0xF, true));
}
__device__ __forceinline__ float dpp_sum32(float s) {
    s += dppf<0x111>(s);
    s += dppf<0x112>(s);
    s += dppf<0x114>(s);
    s += dppf<0x118>(s);
    s += dppf<0x142>(s);   // row_bcast:15 -> totals in lanes 31/63
    return s;
}
__device__ __forceinline__ float dpp_max32(float m) {
    m = fmaxf(m, dppf<0x111>(m));
    m = fmaxf(m, dppf<0x112>(m));
    m = fmaxf(m, dppf<0x114>(m));
    m = fmaxf(m, dppf<0x118>(m));
    m = fmaxf(m, dppf<0x142>(m));
    return m;
}

// ---------------------------------------------------------------------------
// Prep: fold BN scale into conv weights. Outputs:
//  - wpack (f16) in per-lane MFMA A-fragment order:
//      wpack[(((ch2*2+mt)*20+s)*64+ln)*8+j]
//      c = ch2*64 + mt*32 + (ln&31); kk = s>>2; i = (s&3)*16 + (ln>>5)*8 + j
//  - w2f (fp32) [c][kk][i] for the exact F_max refinement
//  - bias2
// ---------------------------------------------------------------------------
__global__ void prep_kernel(const float* __restrict__ conv_w, const float* __restrict__ conv_b,
                            const float* __restrict__ bn_g, const float* __restrict__ bn_b,
                            const float* __restrict__ bn_m, const float* __restrict__ bn_v,
                            unsigned short* __restrict__ wpack, float* __restrict__ w2f,
                            float* __restrict__ bias2)
{
    int e = blockIdx.x * 256 + threadIdx.x;
    if (e < 4 * 20 * 64 * 8) {             // 40960 f16 A-frag entries
        int j    = e & 7;
        int ln   = (e >> 3) & 63;
        int rest = e >> 9;                 // 0..79
        int s    = rest % 20;
        int mt   = (rest / 20) & 1;
        int ch2  = rest / 40;
        int c  = ch2 * 64 + mt * 32 + (ln & 31);
        int kk = s >> 2;
        int i  = (s & 3) * 16 + (ln >> 5) * 8 + j;
        float inv = bn_g[c] * rsqrtf(bn_v[c] + EPSV);
        wpack[e] = f2h(conv_w[(c * IC + i) * KS + kk] * inv);
    }
    if (e < CH * KS * IC) {                // 40960 fp32 [c][kk][i]
        int i  = e & 63;
        int kk = (e >> 6) % KS;
        int c  = e / (KS * IC);
        float inv = bn_g[c] * rsqrtf(bn_v[c] + EPSV);
        w2f[e] = conv_w[(c * IC + i) * KS + kk] * inv;
    }
    if (e < CH) {
        float inv = bn_g[e] * rsqrtf(bn_v[e] + EPSV);
        bias2[e] = (conv_b[e] - bn_m[e]) * inv + bn_b[e];
    }
}

// ---------------------------------------------------------------------------
// Single-pass f16 MFMA conv + BN + ReLU -> f (fp16, ws) + per-channel partial
// sum/max (DPP, from fp32 accumulators). Block = 128c x 128l, 4 waves of
// (64c x 64l). LDS xs[136 rows(l)][64 i] f16, 16B chunks XOR-swizzled (row&7).
// ---------------------------------------------------------------------------
__global__ __launch_bounds__(256, 4)
void conv_mfma_kernel(const float* __restrict__ x,
                      const unsigned short* __restrict__ wpack,
                      const float* __restrict__ bias2,
                      unsigned short* __restrict__ f16,
                      float* __restrict__ psum, float* __restrict__ pmax)
{
    __shared__ unsigned short xs[136 * 64];    // 17,408 B
    const int b   = blockIdx.x;
    const int lt  = blockIdx.y;
    const int l0  = lt * 128;
    const int tid = threadIdx.x;
    const int ln  = tid & 63;
    const int wv  = __builtin_amdgcn_readfirstlane(tid >> 6);

    // ---- staging: wave wv owns i in [wv*16, wv*16+16); lane = row (l) ----
    const float* xb = x + (size_t)b * (IC * LL);
    const int ibase = wv * 16;
    #pragma unroll
    for (int g = 0; g < 3; ++g) {
        int row = g * 64 + ln;
        int l   = l0 - 4 + row;
        if (row < 136) {
            bool vl = (l >= 0) && (l < LL);
            float v[16];
            #pragma unroll
            for (int q = 0; q < 16; ++q)
                v[q] = vl ? xb[(size_t)(ibase + q) * LL + l] : 0.0f;
            unsigned short h[16];
            #pragma unroll
            for (int q = 0; q < 16; ++q) h[q] = f2h(v[q]);
            int rs = row & 7;
            #pragma unroll
            for (int q2 = 0; q2 < 2; ++q2) {     // two 8-f16 (16B) chunks
                int i0    = ibase + q2 * 8;
                int chunk = (i0 >> 3) ^ rs;
                uint4 w4;
                w4.x = (unsigned)h[q2*8+0] | ((unsigned)h[q2*8+1] << 16);
                w4.y = (unsigned)h[q2*8+2] | ((unsigned)h[q2*8+3] << 16);
                w4.z = (unsigned)h[q2*8+4] | ((unsigned)h[q2*8+5] << 16);
                w4.w = (unsigned)h[q2*8+6] | ((unsigned)h[q2*8+7] << 16);
                *(uint4*)&xs[row * 64 + chunk * 8] = w4;
            }
        }
    }
    __syncthreads();

    const int ch2  = wv >> 1;   // c-half
    const int lh   = wv & 1;    // l-half
    const int ln31 = ln & 31;
    const int hi   = ln >> 5;
    const int rowbase = lh * 64 + ln31 + 2;

    const unsigned short* wp  = wpack + (size_t)ln * 8;
    const unsigned short* pA0 = wp + (size_t)((ch2 * 2 + 0) * 20) * 512;  // mt0
    const unsigned short* pA1 = wp + (size_t)((ch2 * 2 + 1) * 20) * 512;  // mt1

    f32x16 acc[2][2];
    #pragma unroll
    for (int mt = 0; mt < 2; ++mt)
        #pragma unroll
        for (int nt = 0; nt < 2; ++nt)
            #pragma unroll
            for (int r = 0; r < 16; ++r) acc[mt][nt][r] = 0.0f;

    auto loadA = [&](f16x8* Av, int s) {
        Av[0] = *(const f16x8*)(pA0 + (size_t)s * 512);
        Av[1] = *(const f16x8*)(pA1 + (size_t)s * 512);
    };
    auto loadB = [&](f16x8* Bv, int s) {
        int kk = s >> 2, iq = s & 3;
        int r0 = rowbase + kk;
        int r1 = r0 + 32;
        int c0 = ((iq << 1) + hi) ^ (r0 & 7);
        int c1 = ((iq << 1) + hi) ^ (r1 & 7);
        Bv[0] = *(const f16x8*)&xs[r0 * 64 + c0 * 8];   // nt0
        Bv[1] = *(const f16x8*)&xs[r1 * 64 + c1 * 8];   // nt1
    };
    auto compute = [&](const f16x8* Av, const f16x8* Bv) {
        acc[0][0] = __builtin_amdgcn_mfma_f32_32x32x16_f16(Av[0], Bv[0], acc[0][0], 0, 0, 0);
        acc[1][0] = __builtin_amdgcn_mfma_f32_32x32x16_f16(Av[1], Bv[0], acc[1][0], 0, 0, 0);
        acc[0][1] = __builtin_amdgcn_mfma_f32_32x32x16_f16(Av[0], Bv[1], acc[0][1], 0, 0, 0);
        acc[1][1] = __builtin_amdgcn_mfma_f32_32x32x16_f16(Av[1], Bv[1], acc[1][1], 0, 0, 0);
    };

    // ---- main loop: 2-deep A/B rings over 20 K-slices ----
    f16x8 Ar[2][2], Br[2][2];
    loadA(Ar[0], 0); loadB(Br[0], 0);
    #pragma unroll
    for (int s = 0; s < 20; ++s) {
        if (s + 1 < 20) { loadA(Ar[(s + 1) & 1], s + 1); loadB(Br[(s + 1) & 1], s + 1); }
        compute(Ar[s & 1], Br[s & 1]);
    }

    // ---- epilogue: bias + relu, store f16, per-channel partial sum/max ----
    // D mapping (32x32): col(l)=ln&31, row(c)=(r&3)+8*(r>>2)+4*(ln>>5)
    const int lgbase = l0 + lh * 64 + ln31;
    #pragma unroll
    for (int mt = 0; mt < 2; ++mt) {
        #pragma unroll
        for (int nt = 0; nt < 2; ++nt) {
            #pragma unroll
            for (int r = 0; r < 16; ++r) {
                int c = ch2 * 64 + mt * 32 + (r & 3) + 8 * (r >> 2) + 4 * hi;
                float fv = fmaxf(acc[mt][nt][r] + bias2[c], 0.0f);
                f16[((size_t)(b * CH + c)) * LL + lgbase + nt * 32] = f2h(fv);
                acc[mt][nt][r] = fv;
            }
        }
    }
    #pragma unroll
    for (int mt = 0; mt < 2; ++mt) {
        #pragma unroll
        for (int r = 0; r < 16; ++r) {
            float s = dpp_sum32(acc[mt][0][r] + acc[mt][1][r]);
            float m = dpp_max32(fmaxf(acc[mt][0][r], acc[mt][1][r]));
            if (ln31 == 31) {
                int c   = ch2 * 64 + mt * 32 + (r & 3) + 8 * (r >> 2) + 4 * hi;
                int lt2 = lt * 2 + lh;
                psum[(b * CH + c) * NLT2 + lt2] = s;
                pmax[(b * CH + c) * NLT2 + lt2] = m;
            }
        }
    }
}

// ---------------------------------------------------------------------------
// fixmax v2: per (b,c) — 256 threads (4 waves). Thread t owns slot t for the
// M / sum reduction (coalesced). Candidate slots (pmax within EPSR of M) are
// collected into an LDS list (no cap — the argmax slot always qualifies) and
// recomputed exactly in fp32 VALU conv, one slot per WAVE round-robin
// (lane = l, coalesced 256B loads; x is L3-resident). Deterministic: max is
// order-independent, sum uses a fixed reduction order.
// fadd = (alpha+0.5)*F_avg + (beta+0.5)*F_max_exact.
// ---------------------------------------------------------------------------
__global__ __launch_bounds__(256)
void fixmax_kernel(const float* __restrict__ x, const float* __restrict__ w2f,
                   const float* __restrict__ bias2,
                   const float* __restrict__ psum, const float* __restrict__ pmax,
                   const float* __restrict__ alpha, const float* __restrict__ beta,
                   float* __restrict__ fadd)
{
    __shared__ float wm[4], wsum[4], wfm[4];
    __shared__ int candList[NLT2];
    __shared__ int ncand;
    const int c   = blockIdx.x;
    const int b   = blockIdx.y;
    const int tid = threadIdx.x;
    const int ln  = tid & 63;
    const int wv  = tid >> 6;

    const float* ps = psum + (size_t)(b * CH + c) * NLT2;
    const float* pm = pmax + (size_t)(b * CH + c) * NLT2;
    float pmv = pm[tid];
    float psv = ps[tid];

    float m = pmv, s = psv;
    #pragma unroll
    for (int off = 1; off <= 32; off <<= 1) {
        s += __shfl_xor(s, off, 64);
        m = fmaxf(m, __shfl_xor(m, off, 64));
    }
    if (tid == 0) ncand = 0;
    if (ln == 0) { wm[wv] = m; wsum[wv] = s; }
    __syncthreads();
    float M    = fmaxf(fmaxf(wm[0], wm[1]), fmaxf(wm[2], wm[3]));
    float stot = (wsum[0] + wsum[1]) + (wsum[2] + wsum[3]);

    if (pmv >= M - EPSR) { int k = atomicAdd(&ncand, 1); candList[k] = tid; }
    __syncthreads();
    const int nc = ncand;

    const float* xb  = x + (size_t)b * (IC * LL);
    const float* w2c = w2f + (size_t)c * (KS * IC);
    const float bsc  = bias2[c];
    float Fm = 0.0f;                        // relu => exact max >= 0
    for (int k = wv; k < nc; k += 4) {
        int slot = candList[k];
        int l    = (slot >> 1) * 128 + (slot & 1) * 64 + ln;
        float fe = bsc;
        #pragma unroll
        for (int kk = 0; kk < KS; ++kk) {
            int lidx = l + kk - 2;
            bool v = (lidx >= 0) && (lidx < LL);
            const float* xr = xb + lidx;
            const float* wr = w2c + kk * IC;
            #pragma unroll 16
            for (int i = 0; i < IC; ++i) {
                float xv = v ? xr[(size_t)i * LL] : 0.0f;
                fe = fmaf(xv, wr[i], fe);
            }
        }
        fe = fmaxf(fe, 0.0f);
        #pragma unroll
        for (int off = 1; off <= 32; off <<= 1)
            fe = fmaxf(fe, __shfl_xor(fe, off, 64));
        Fm = fmaxf(Fm, fe);
    }
    if (ln == 0) wfm[wv] = Fm;
    __syncthreads();
    if (tid == 0) {
        float Fmax = fmaxf(fmaxf(wfm[0], wfm[1]), fmaxf(wfm[2], wfm[3]));
        float favg = stot * (1.0f / LL);
        fadd[b * CH + c] = (alpha[0] + 0.5f) * favg + (beta[0] + 0.5f) * Fmax;
    }
}

// ---------------------------------------------------------------------------
// chan2: per batch — channel attention (5-tap conv over C + sigmoid) from
// fadd, then top-K mask via rank count (ties by lower index = jax.lax.top_k).
// ---------------------------------------------------------------------------
__global__ void chan2_kernel(const float* __restrict__ fadd,
                             const float* __restrict__ ca_w, const float* __restrict__ ca_b,
                             float* __restrict__ cm, float* __restrict__ maskv)
{
    int b = blockIdx.x;
    int c = threadIdx.x;   // 128
    __shared__ float fa[CH];
    __shared__ float cms[CH];
    fa[c] = fadd[b * CH + c];
    __syncthreads();

    float z = ca_b[0];
    #pragma unroll
    for (int k = 0; k < CAK; ++k) {
        int cc = c + k - 2;
        float v = (cc >= 0 && cc < CH) ? fa[cc] : 0.0f;
        z = fmaf(ca_w[k], v, z);
    }
    float cmv = 1.0f / (1.0f + expf(-z));
    cms[c] = cmv;
    __syncthreads();

    int rank = 0;
    for (int cc = 0; cc < CH; ++cc) {
        float o = cms[cc];
        rank += (o > cmv || (o == cmv && cc < c)) ? 1 : 0;
    }
    cm[b * CH + c] = cmv;
    maskv[b * CH + c] = (rank < KCR) ? 1.0f : 0.0f;
}

// ---------------------------------------------------------------------------
// Fused stats + gate + final, vectorized x2 along l.
// ---------------------------------------------------------------------------
__global__ __launch_bounds__(256)
void sgf_kernel(const unsigned short* __restrict__ f16, float* __restrict__ out,
                const float* __restrict__ cm, const float* __restrict__ maskv,
                const float* __restrict__ sa_w,
                const float* __restrict__ sabn_g, const float* __restrict__ sabn_b,
                const float* __restrict__ sabn_m, const float* __restrict__ sabn_v)
{
    __shared__ float cms[CH], mks[CH];
    __shared__ float st[4][520];
    const int g   = blockIdx.x;    // 0..31 (512-l tile)
    const int b   = blockIdx.y;
    const int l0  = g * 512;
    const int tid = threadIdx.x;
    if (tid < CH) { cms[tid] = cm[b * CH + tid]; mks[tid] = maskv[b * CH + tid]; }
    __syncthreads();

    {
        const unsigned short* fb = f16 + (size_t)b * CH * LL + l0 + 2 * tid;
        float cmx0 = 0.f, csm0 = 0.f, smx0 = 0.f, ssm0 = 0.f;
        float cmx1 = 0.f, csm1 = 0.f, smx1 = 0.f, ssm1 = 0.f;
        #pragma unroll 4
        for (int c = 0; c < CH; ++c) {
            unsigned pr = *(const unsigned*)(fb + (size_t)c * LL);
            float cmc = cms[c], mk = mks[c];
            float v0 = h2f((unsigned short)(pr & 0xFFFFu)) * cmc;
            float v1 = h2f((unsigned short)(pr >> 16)) * cmc;
            float vs0 = v0 * mk, vu0 = v0 - vs0;
            float vs1 = v1 * mk, vu1 = v1 - vs1;
            cmx0 = fmaxf(cmx0, vs0); smx0 = fmaxf(smx0, vu0); csm0 += vs0; ssm0 += vu0;
            cmx1 = fmaxf(cmx1, vs1); smx1 = fmaxf(smx1, vu1); csm1 += vs1; ssm1 += vu1;
        }
        int s0 = 3 + 2 * tid;
        st[0][s0] = cmx0;                  st[0][s0 + 1] = cmx1;
        st[1][s0] = csm0 * (1.0f / KCR);   st[1][s0 + 1] = csm1 * (1.0f / KCR);
        st[2][s0] = smx0;                  st[2][s0 + 1] = smx1;
        st[3][s0] = ssm0 * (1.0f / (CH - KCR));
        st[3][s0 + 1] = ssm1 * (1.0f / (CH - KCR));
    }
    if (tid < 6) {
        int slot = (tid < 3) ? tid : 515 + (tid - 3);
        int l = l0 - 3 + slot;
        float cmx = 0.f, csm = 0.f, smx = 0.f, ssm = 0.f;
        if (l >= 0 && l < LL) {
            const unsigned short* fb = f16 + (size_t)b * CH * LL + l;
            for (int c = 0; c < CH; ++c) {
                float v  = h2f(fb[(size_t)c * LL]) * cms[c];
                float mk = mks[c];
                float vs = v * mk, vu = v - vs;
                cmx = fmaxf(cmx, vs); smx = fmaxf(smx, vu);
                csm += vs; ssm += vu;
            }
        }
        st[0][slot] = cmx;
        st[1][slot] = csm * (1.0f / KCR);
        st[2][slot] = smx;
        st[3][slot] = ssm * (1.0f / (CH - KCR));
    }
    __syncthreads();

    float inv = sabn_g[0] * rsqrtf(sabn_v[0] + EPSV);
    float bb2 = sabn_b[0] - sabn_m[0] * inv;
    float y1a = 0.f, y2a = 0.f, y1b = 0.f, y2b = 0.f;
    #pragma unroll
    for (int k = 0; k < 7; ++k) {
        float wm = sa_w[k], wa = sa_w[7 + k];
        int s0 = 2 * tid + k;
        y1a = fmaf(wm, st[0][s0],     fmaf(wa, st[1][s0],     y1a));
        y2a = fmaf(wm, st[2][s0],     fmaf(wa, st[3][s0],     y2a));
        y1b = fmaf(wm, st[0][s0 + 1], fmaf(wa, st[1][s0 + 1], y1b));
        y2b = fmaf(wm, st[2][s0 + 1], fmaf(wa, st[3][s0 + 1], y2b));
    }
    float A1a = 1.0f / (1.0f + expf(-fmaxf(y1a * inv + bb2, 0.f)));
    float A2a = 1.0f / (1.0f + expf(-fmaxf(y2a * inv + bb2, 0.f)));
    float A1b = 1.0f / (1.0f + expf(-fmaxf(y1b * inv + bb2, 0.f)));
    float A2b = 1.0f / (1.0f + expf(-fmaxf(y2b * inv + bb2, 0.f)));

    const unsigned short* fb = f16 + (size_t)b * CH * LL + l0 + 2 * tid;
    float* ob = out + (size_t)b * CH * LL + l0 + 2 * tid;
    #pragma unroll 4
    for (int c = 0; c < CH; ++c) {
        unsigned pr = *(const unsigned*)(fb + (size_t)c * LL);
        float cmc = cms[c];
        float v0 = h2f((unsigned short)(pr & 0xFFFFu)) * cmc;
        float v1 = h2f((unsigned short)(pr >> 16)) * cmc;
        bool sel = (mks[c] > 0.5f);
        float2 w;
        w.x = v0 * (sel ? A1a : A2a);
        w.y = v1 * (sel ? A1b : A2b);
        *(float2*)(ob + (size_t)c * LL) = w;
    }
}

extern "C" void kernel_launch(void* const* d_in, const int* in_sizes, int n_in,
                              void* d_out, int out_size, void* d_ws, size_t ws_size,
                              hipStream_t stream)
{
    const float* x      = (const float*)d_in[0];
    const float* conv_w = (const float*)d_in[1];
    const float* conv_b = (const float*)d_in[2];
    const float* bn_g   = (const float*)d_in[3];
    const float* bn_b   = (const float*)d_in[4];
    const float* bn_m   = (const float*)d_in[5];
    const float* bn_v   = (const float*)d_in[6];
    const float* alpha  = (const float*)d_in[7];
    const float* beta   = (const float*)d_in[8];
    const float* ca_w   = (const float*)d_in[9];
    const float* ca_b   = (const float*)d_in[10];
    const float* sa_w   = (const float*)d_in[11];
    const float* sabn_g = (const float*)d_in[12];
    const float* sabn_b = (const float*)d_in[13];
    const float* sabn_m = (const float*)d_in[14];
    const float* sabn_v = (const float*)d_in[15];

    float* out = (float*)d_out;
    float* ws  = (float*)d_ws;

    unsigned short* wpack = (unsigned short*)(ws + OFF_WPACK);
    float* w2f   = ws + OFF_W2F;
    float* bias2 = ws + OFF_BIAS2;
    float* psum  = ws + OFF_PSUM;
    float* pmax  = ws + OFF_PMAX;
    float* faddp = ws + OFF_FADD;
    float* cmv_  = ws + OFF_CM;
    float* mskv  = ws + OFF_MASK;
    unsigned short* f16p = (unsigned short*)(ws + OFF_F16);

    prep_kernel<<<160, 256, 0, stream>>>(conv_w, conv_b, bn_g, bn_b, bn_m, bn_v,
                                         wpack, w2f, bias2);

    conv_mfma_kernel<<<dim3(BB, 128), 256, 0, stream>>>(x, wpack, bias2, f16p, psum, pmax);

    fixmax_kernel<<<dim3(CH, BB), 256, 0, stream>>>(x, w2f, bias2, psum, pmax,
                                                    alpha, beta, faddp);

    chan2_kernel<<<BB, CH, 0, stream>>>(faddp, ca_w, ca_b, cmv_, mskv);

    sgf_kernel<<<dim3(32, BB), 256, 0, stream>>>(f16p, out, cmv_, mskv, sa_w,
                                                 sabn_g, sabn_b, sabn_m, sabn_v);
}